// Round 6
// baseline (475.431 us; speedup 1.0000x reference)
//
#include <hip/hip_runtime.h>
#include <math.h>

#define NB 32          // MAX_NODES
#define BATCH 16384
#define MPB 8          // matrices per block
#define TPB (MPB * 32) // 256 threads, 4 waves

// ws layout (16 B, zeroed by hipMemsetAsync): [0]=bce_sum [1]=mask_sum [2]=phys_sum [3]=unused

// ---- DPP cross-lane helpers (VALU pipe, not DS pipe) ----
// row_ror:N rotates within each 16-lane row; rotation-butterfly over
// {1,2,4,8} gives a full 16-lane reduce-to-all (circulant reduction).
template<int CTRL>
__device__ __forceinline__ float dpp_add(float v) {
    const int s = __float_as_int(v);
    const int r = __builtin_amdgcn_update_dpp(s, s, CTRL, 0xF, 0xF, false);
    return v + __int_as_float(r);
}
template<int CTRL>
__device__ __forceinline__ float dpp_min(float v) {
    const int s = __float_as_int(v);
    const int r = __builtin_amdgcn_update_dpp(s, s, CTRL, 0xF, 0xF, false);
    return fminf(v, __int_as_float(r));
}
template<int CTRL>
__device__ __forceinline__ float dpp_max(float v) {
    const int s = __float_as_int(v);
    const int r = __builtin_amdgcn_update_dpp(s, s, CTRL, 0xF, 0xF, false);
    return fmaxf(v, __int_as_float(r));
}
// sum over each 32-lane group, result in all lanes: 4 DPP adds + 1 swizzle
__device__ __forceinline__ float grp32_sum(float v) {
    v = dpp_add<0x121>(v);   // row_ror:1
    v = dpp_add<0x122>(v);   // row_ror:2
    v = dpp_add<0x124>(v);   // row_ror:4
    v = dpp_add<0x128>(v);   // row_ror:8  -> 16-row total in every lane
    v += __shfl_xor(v, 16, 64);
    return v;
}
__device__ __forceinline__ float grp32_min(float v) {
    v = dpp_min<0x121>(v); v = dpp_min<0x122>(v);
    v = dpp_min<0x124>(v); v = dpp_min<0x128>(v);
    return fminf(v, __shfl_xor(v, 16, 64));
}
__device__ __forceinline__ float grp32_max(float v) {
    v = dpp_max<0x121>(v); v = dpp_max<0x122>(v);
    v = dpp_max<0x124>(v); v = dpp_max<0x128>(v);
    return fmaxf(v, __shfl_xor(v, 16, 64));
}

// 8 matrices per 256-thread block (each 32-lane group owns one matrix).
// Round-6 change (R5 post-mortem: allocator clamps to 64 VGPR and spills
// a[32]+xv[32]+temps to scratch; scratch backing store caps residency at
// ~10 waves/CU -> every round stuck 360-455us):
//   DELETE the xv[NB] register array. The rank-2 update reads BOTH v and p
//   from the pre-masked LDS arrays as uniform-address ds_read_b128
//   broadcasts. Phase-3 live state = a[32] + ~15 temps < 64 VGPR -> the
//   allocator's 64-reg target is now satisfiable with ZERO spill.
//   sv/sp single-buffered: all producers/consumers of one matrix are the
//   same 32 lanes of the same wave -> DS program order suffices.
// Hard row guard j>=k kept verbatim (round-2 lesson); masked LDS values are
// exact zeros feeding multiplies only.
__global__ __launch_bounds__(TPB, 2)
void lap_main(const float* __restrict__ predA, const float* __restrict__ targA,
              const float* __restrict__ nmask, float* __restrict__ out,
              float* __restrict__ ws)
{
    __shared__ float sv[MPB][NB];       // masked Householder v (0 for j<=k)
    __shared__ float sp[MPB][NB];       // masked p (0 for j<k)
    __shared__ float sde[MPB][NB][2];   // [i][0]=d_i, [i][1]=e2_{i-1}

    const int t    = threadIdx.x;           // 0..255
    const int j    = t & 31;                // row index within matrix
    const int mm   = t >> 5;                // matrix within block (0..7)
    const int half = mm & 1;                // 32-lane half within the wave
    const int b    = blockIdx.x * MPB + mm; // batch index
    const size_t base = (size_t)b * (NB * NB);

    // ---- phase 1: per-lane row loads, BCE partials, pred row -> a[] ----
    const float  mr  = nmask[(size_t)blockIdx.x * (MPB * NB) + t];
    const float4* pr4 = (const float4*)(predA + base + (size_t)j * NB);
    const float4* tr4 = (const float4*)(targA + base + (size_t)j * NB);
    const float4* nm4 = (const float4*)(nmask + (size_t)b * NB);

    float a[NB];
    float accB = 0.f, accM = 0.f;
    #pragma unroll
    for (int q = 0; q < 8; ++q) {
        const float4 p  = pr4[q];
        const float4 tg = tr4[q];
        const float4 mc = nm4[q];
        const float bx = -(tg.x * __logf(p.x) + (1.f - tg.x) * __logf(1.f - p.x));
        const float by = -(tg.y * __logf(p.y) + (1.f - tg.y) * __logf(1.f - p.y));
        const float bz = -(tg.z * __logf(p.z) + (1.f - tg.z) * __logf(1.f - p.z));
        const float bw = -(tg.w * __logf(p.w) + (1.f - tg.w) * __logf(1.f - p.w));
        accB += mr * (mc.x * bx + mc.y * by + mc.z * bz + mc.w * bw);
        accM += mr * (mc.x + mc.y + mc.z + mc.w);
        a[4*q+0] = p.x; a[4*q+1] = p.y; a[4*q+2] = p.z; a[4*q+3] = p.w;
    }
    accB = grp32_sum(accB); accB += __shfl_xor(accB, 32, 64);
    accM = grp32_sum(accM); accM += __shfl_xor(accM, 32, 64);
    if ((t & 63) == 0) { atomicAdd(ws + 0, accB); atomicAdd(ws + 1, accM); }

    // ---- phase 2: M = (L+L^T)/2 in place; col coalesced from global ----
    float dsum = 0.f, pdiag = 0.f;
    #pragma unroll
    for (int i = 0; i < NB; ++i) {
        dsum += a[i];
        pdiag = (i == j) ? a[i] : pdiag;
    }
    const float jitter = 1e-5f + (9e-5f / 31.f) * (float)j;
    const float dval = dsum + jitter - pdiag;
    #pragma unroll
    for (int i = 0; i < NB; ++i) {
        const float cv = predA[base + (size_t)i * NB + j];  // coalesced across lanes
        const float s  = -0.5f * (a[i] + cv);
        a[i] = (i == j) ? dval : s;
    }

    // ---- phase 3: Householder, rolled; LDS b128 broadcasts + DPP reduces ----
    float colk = a[0];                      // lane j holds A[j][k] for current k
    const float4* sv4 = (const float4*)&sv[mm][0];
    const float4* sp4 = (const float4*)&sp[mm][0];
    for (int k = 0; k < NB - 2; ++k) {
        const float sg = grp32_sum((j > k) ? colk * colk : 0.f);
        const float x1 = __shfl(colk, k + 1, 32);
        const float al = (x1 >= 0.f) ? -sqrtf(sg) : sqrtf(sg);
        const float denom = sg - al * x1;
        const float beta  = (denom > 1e-30f) ? __builtin_amdgcn_rcpf(denom) : 0.f;
        // vj includes the (j==k+1) -al fixup -> LDS v needs no read-side fixup
        const float vj = (j > k) ? (colk - ((j == k + 1) ? al : 0.f)) : 0.f;
        sv[mm][j] = vj;                     // pre-masked: exact 0 for j<=k

        // dot = a_row . v via uniform-address b128 broadcast reads
        float ac0 = 0.f, ac1 = 0.f, ac2 = 0.f, ac3 = 0.f;
        #pragma unroll
        for (int q = 0; q < 8; ++q) {
            if (4*q + 3 >= k) {             // wave-uniform chunk skip
                const float4 x = sv4[q];
                ac0 += a[4*q+0] * x.x;
                ac1 += a[4*q+1] * x.y;
                ac2 += a[4*q+2] * x.z;
                ac3 += a[4*q+3] * x.w;
            }
        }
        const float dot = (ac0 + ac1) + (ac2 + ac3);
        const float pj  = beta * dot;
        const float pjm = (j >= k) ? pj : 0.f;     // frozen lanes publish 0
        sp[mm][j] = pjm;
        const float K   = grp32_sum(vj * pjm);
        const float c   = 0.5f * beta * K;
        const float s2  = pjm - 2.f * c * vj;
        const float nvj = -vj, ns2 = -s2;

        // rank-2 update under HARD row guard: frozen rows provably untouched.
        // v and p both re-read from LDS (uniform-address broadcast) -> no
        // xv[] register array, phase-3 live state fits 64 VGPR.
        float ncol = colk;
        if (j >= k) {
            #pragma unroll
            for (int q = 0; q < 8; ++q) {
                if (4*q + 3 >= k) {
                    const float4 x4 = sv4[q];
                    const float4 p4 = sp4[q];
                    #pragma unroll
                    for (int u = 0; u < 4; ++u) {
                        const int i = 4*q + u;
                        if (i >= k) {                       // uniform cond
                            const float xvi = (u == 0) ? x4.x : (u == 1) ? x4.y
                                            : (u == 2) ? x4.z : x4.w;
                            const float pvi = (u == 0) ? p4.x : (u == 1) ? p4.y
                                            : (u == 2) ? p4.z : p4.w;
                            float av = a[i];
                            av = fmaf(nvj, pvi, av);
                            av = fmaf(ns2, xvi, av);
                            a[i] = av;
                            ncol = (i == k + 1) ? av : ncol; // carry col k+1
                        }
                    }
                }
            }
        }
        colk = ncol;
    }

    // ---- extraction: lane j keeps d_j = A[j][j], e_{j-1} = A[j][j-1] ----
    float dloc = 0.f, eloc = 0.f;
    #pragma unroll
    for (int i = 0; i < NB; ++i) {
        dloc = (i == j)     ? a[i] : dloc;
        eloc = (i == j - 1) ? a[i] : eloc;   // lane 0 keeps 0
    }

    // Gershgorin bounds via DPP min/max reduce
    const float aej = fabsf(eloc);                       // |e_{j-1}|
    const float aer = __shfl(aej, (j + 1) & 31, 32);     // |e_j| (lane31 -> 0)
    float lo = grp32_min(dloc - (aej + aer));
    float hi = grp32_max(dloc + (aej + aer));

    // publish d/e2 to LDS (same-wave producer/consumer, DS program order)
    *(float2*)&sde[mm][j][0] = make_float2(dloc, eloc * eloc);

    // ---- phase 4: Sturm multisection (32 sigmas/round, 3 rounds) ----
    const float2* de2 = (const float2*)&sde[mm][0][0];
    for (int round = 0; round < 3; ++round) {
        asm volatile("" ::: "memory");   // force reload per round (no reg CSE)
        const float step = (hi - lo) * (1.f / 33.f);
        const float sig = lo + step * (float)(j + 1);
        const float2 d0 = de2[0];
        float q = d0.x - sig;
        int cnt = (q < 0.f);
        #pragma unroll
        for (int i = 1; i < NB; ++i) {
            const float2 di = de2[i];     // hoistable within the round
            if (fabsf(q) < 1e-20f) q = (q < 0.f) ? -1e-20f : 1e-20f;
            q = (di.x - sig) - di.y * __builtin_amdgcn_rcpf(q);
            cnt += (q < 0.f);
        }
        const unsigned long long bal = __ballot(cnt >= 2);
        const unsigned int bits = (unsigned int)(bal >> (half * 32));
        const int jstar = (bits == 0u) ? 32 : __builtin_ctz(bits);
        const float nlo = lo + step * (float)jstar;
        const float nhi = lo + step * (float)(jstar + 1);
        lo = nlo; hi = nhi;
    }
    const float lam2 = 0.5f * (lo + hi);

    if (j == 0) out[2 + b] = lam2;
    const float ph = fmaxf(0.1f - lam2, 0.f);
    const float ph0 = __shfl(ph, 0, 64);
    const float ph1 = __shfl(ph, 32, 64);
    if ((t & 63) == 0) atomicAdd(ws + 2, ph0 + ph1);   // one add per wave (2 matrices)
}

__global__ __launch_bounds__(64)
void lap_final(float* __restrict__ out, const float* __restrict__ ws) {
    if (threadIdx.x == 0) {
        out[0] = ws[0] / fmaxf(ws[1], 1.f);
        out[1] = ws[2] * (1.f / (float)BATCH);
    }
}

extern "C" void kernel_launch(void* const* d_in, const int* in_sizes, int n_in,
                              void* d_out, int out_size, void* d_ws, size_t ws_size,
                              hipStream_t stream) {
    const float* pred = (const float*)d_in[0];
    const float* targ = (const float*)d_in[1];
    const float* nm   = (const float*)d_in[2];
    float* out = (float*)d_out;
    float* ws  = (float*)d_ws;

    (void)hipMemsetAsync(d_ws, 0, 16, stream);
    hipLaunchKernelGGL(lap_main, dim3(BATCH / MPB), dim3(TPB), 0, stream,
                       pred, targ, nm, out, ws);
    hipLaunchKernelGGL(lap_final, dim3(1), dim3(64), 0, stream, out, ws);
}

// Round 7
// 430.827 us; speedup vs baseline: 1.1035x; 1.1035x over previous
//
#include <hip/hip_runtime.h>
#include <math.h>

#define NB 32          // MAX_NODES
#define BATCH 16384
#define MPB 16         // matrices per block: 2 per 32-lane group (ILP pair)
#define TPB 256        // 8 groups, 4 waves

// ws layout (16 B, zeroed by hipMemsetAsync): [0]=bce_sum [1]=mask_sum [2]=phys_sum [3]=unused

// ---- DPP cross-lane helpers (VALU pipe, not DS pipe) ----
template<int CTRL>
__device__ __forceinline__ float dpp_add(float v) {
    const int s = __float_as_int(v);
    const int r = __builtin_amdgcn_update_dpp(s, s, CTRL, 0xF, 0xF, false);
    return v + __int_as_float(r);
}
template<int CTRL>
__device__ __forceinline__ float dpp_min(float v) {
    const int s = __float_as_int(v);
    const int r = __builtin_amdgcn_update_dpp(s, s, CTRL, 0xF, 0xF, false);
    return fminf(v, __int_as_float(r));
}
template<int CTRL>
__device__ __forceinline__ float dpp_max(float v) {
    const int s = __float_as_int(v);
    const int r = __builtin_amdgcn_update_dpp(s, s, CTRL, 0xF, 0xF, false);
    return fmaxf(v, __int_as_float(r));
}
__device__ __forceinline__ float grp32_sum(float v) {
    v = dpp_add<0x121>(v);   // row_ror:1
    v = dpp_add<0x122>(v);   // row_ror:2
    v = dpp_add<0x124>(v);   // row_ror:4
    v = dpp_add<0x128>(v);   // row_ror:8
    v += __shfl_xor(v, 16, 64);
    return v;
}
__device__ __forceinline__ float grp32_min(float v) {
    v = dpp_min<0x121>(v); v = dpp_min<0x122>(v);
    v = dpp_min<0x124>(v); v = dpp_min<0x128>(v);
    return fminf(v, __shfl_xor(v, 16, 64));
}
__device__ __forceinline__ float grp32_max(float v) {
    v = dpp_max<0x121>(v); v = dpp_max<0x122>(v);
    v = dpp_max<0x124>(v); v = dpp_max<0x128>(v);
    return fmaxf(v, __shfl_xor(v, 16, 64));
}

// Round-7: TWO matrices per 32-lane group (ILP pair A/B). Cross-round
// post-mortem: per-wave serialized latency is ~constant 27-34k cycles in
// every structure tried => serial dependency chain per matrix is the floor.
// Two independent chains per thread interleave at instruction level and
// cover ~2x work per unit latency. Register budget aA[32]+aB[32]+temps
// ~110 VGPR; amdgpu_waves_per_eu(4,4) pins the allocator to the 128-reg /
// 4-waves-per-EU tier (max=4 removes its incentive to clamp to 64 and
// spill -- the R3/R5/R6 failure). Broadcast structure is verbatim R6:
// pre-masked LDS v/p, uniform-address b128 broadcast reads, HARD row
// guard (round-2 lesson), DPP reduces on the VALU pipe.
__global__ __attribute__((amdgpu_flat_work_group_size(TPB, TPB),
                          amdgpu_waves_per_eu(4, 4)))
void lap_main(const float* __restrict__ predA, const float* __restrict__ targA,
              const float* __restrict__ nmask, float* __restrict__ out,
              float* __restrict__ ws)
{
    __shared__ float sv[8][2][NB];      // masked Householder v (0 for j<=k)
    __shared__ float sp[8][2][NB];      // masked p (0 for j<k)
    __shared__ float sde[8][2][NB][2];  // [i][0]=d_i, [i][1]=e2_{i-1}

    const int t    = threadIdx.x;           // 0..255
    const int j    = t & 31;                // row index within matrix
    const int g    = t >> 5;                // group (0..7)
    const int half = g & 1;                 // 32-lane half within the wave
    const int bA   = blockIdx.x * MPB + g * 2;
    const int bB   = bA + 1;
    const size_t baseA = (size_t)bA * (NB * NB);
    const size_t baseB = (size_t)bB * (NB * NB);

    // ---- phase 1: row loads + BCE partials, A then B (caps reg pressure) ----
    const float mrA = nmask[(size_t)bA * NB + j];
    const float mrB = nmask[(size_t)bB * NB + j];
    const float4* prA = (const float4*)(predA + baseA + (size_t)j * NB);
    const float4* trA = (const float4*)(targA + baseA + (size_t)j * NB);
    const float4* nmA = (const float4*)(nmask + (size_t)bA * NB);
    const float4* prB = (const float4*)(predA + baseB + (size_t)j * NB);
    const float4* trB = (const float4*)(targA + baseB + (size_t)j * NB);
    const float4* nmB = (const float4*)(nmask + (size_t)bB * NB);

    float aA[NB], aB[NB];
    float accB = 0.f, accM = 0.f;
    #pragma unroll
    for (int q = 0; q < 8; ++q) {
        const float4 p  = prA[q];
        const float4 tg = trA[q];
        const float4 mc = nmA[q];
        const float bx = -(tg.x * __logf(p.x) + (1.f - tg.x) * __logf(1.f - p.x));
        const float by = -(tg.y * __logf(p.y) + (1.f - tg.y) * __logf(1.f - p.y));
        const float bz = -(tg.z * __logf(p.z) + (1.f - tg.z) * __logf(1.f - p.z));
        const float bw = -(tg.w * __logf(p.w) + (1.f - tg.w) * __logf(1.f - p.w));
        accB += mrA * (mc.x * bx + mc.y * by + mc.z * bz + mc.w * bw);
        accM += mrA * (mc.x + mc.y + mc.z + mc.w);
        aA[4*q+0] = p.x; aA[4*q+1] = p.y; aA[4*q+2] = p.z; aA[4*q+3] = p.w;
    }
    #pragma unroll
    for (int q = 0; q < 8; ++q) {
        const float4 p  = prB[q];
        const float4 tg = trB[q];
        const float4 mc = nmB[q];
        const float bx = -(tg.x * __logf(p.x) + (1.f - tg.x) * __logf(1.f - p.x));
        const float by = -(tg.y * __logf(p.y) + (1.f - tg.y) * __logf(1.f - p.y));
        const float bz = -(tg.z * __logf(p.z) + (1.f - tg.z) * __logf(1.f - p.z));
        const float bw = -(tg.w * __logf(p.w) + (1.f - tg.w) * __logf(1.f - p.w));
        accB += mrB * (mc.x * bx + mc.y * by + mc.z * bz + mc.w * bw);
        accM += mrB * (mc.x + mc.y + mc.z + mc.w);
        aB[4*q+0] = p.x; aB[4*q+1] = p.y; aB[4*q+2] = p.z; aB[4*q+3] = p.w;
    }
    accB = grp32_sum(accB); accB += __shfl_xor(accB, 32, 64);
    accM = grp32_sum(accM); accM += __shfl_xor(accM, 32, 64);
    if ((t & 63) == 0) { atomicAdd(ws + 0, accB); atomicAdd(ws + 1, accM); }

    // ---- phase 2: M = (L+L^T)/2 in place; col coalesced from global ----
    float dsA = 0.f, pdA = 0.f, dsB = 0.f, pdB = 0.f;
    #pragma unroll
    for (int i = 0; i < NB; ++i) {
        dsA += aA[i]; pdA = (i == j) ? aA[i] : pdA;
        dsB += aB[i]; pdB = (i == j) ? aB[i] : pdB;
    }
    const float jitter = 1e-5f + (9e-5f / 31.f) * (float)j;
    const float dvA = dsA + jitter - pdA;
    const float dvB = dsB + jitter - pdB;
    #pragma unroll
    for (int i = 0; i < NB; ++i) {
        const float cvA = predA[baseA + (size_t)i * NB + j];  // coalesced
        const float cvB = predA[baseB + (size_t)i * NB + j];
        aA[i] = (i == j) ? dvA : -0.5f * (aA[i] + cvA);
        aB[i] = (i == j) ? dvB : -0.5f * (aB[i] + cvB);
    }

    // ---- phase 3: Householder, two interleaved chains, LDS b128 bcasts ----
    float colA = aA[0], colB = aB[0];
    float* svA = &sv[g][0][0]; float* svB = &sv[g][1][0];
    float* spA = &sp[g][0][0]; float* spB = &sp[g][1][0];
    const float4* svA4 = (const float4*)svA; const float4* svB4 = (const float4*)svB;
    const float4* spA4 = (const float4*)spA; const float4* spB4 = (const float4*)spB;
    for (int k = 0; k < NB - 2; ++k) {
        const float sgA = grp32_sum((j > k) ? colA * colA : 0.f);
        const float sgB = grp32_sum((j > k) ? colB * colB : 0.f);
        const float x1A = __shfl(colA, k + 1, 32);
        const float x1B = __shfl(colB, k + 1, 32);
        const float alA = (x1A >= 0.f) ? -sqrtf(sgA) : sqrtf(sgA);
        const float alB = (x1B >= 0.f) ? -sqrtf(sgB) : sqrtf(sgB);
        const float deA = sgA - alA * x1A;
        const float deB = sgB - alB * x1B;
        const float beA = (deA > 1e-30f) ? __builtin_amdgcn_rcpf(deA) : 0.f;
        const float beB = (deB > 1e-30f) ? __builtin_amdgcn_rcpf(deB) : 0.f;
        const float vjA = (j > k) ? (colA - ((j == k + 1) ? alA : 0.f)) : 0.f;
        const float vjB = (j > k) ? (colB - ((j == k + 1) ? alB : 0.f)) : 0.f;
        svA[j] = vjA;                   // pre-masked: exact 0 for j<=k
        svB[j] = vjB;

        // dots via uniform-address b128 broadcast reads (wave-uniform skip)
        float a0 = 0.f, a1 = 0.f, a2 = 0.f, a3 = 0.f;
        float b0 = 0.f, b1 = 0.f, b2 = 0.f, b3 = 0.f;
        #pragma unroll
        for (int q = 0; q < 8; ++q) {
            if (4*q + 3 >= k) {
                const float4 xA = svA4[q];
                const float4 xB = svB4[q];
                a0 += aA[4*q+0] * xA.x; a1 += aA[4*q+1] * xA.y;
                a2 += aA[4*q+2] * xA.z; a3 += aA[4*q+3] * xA.w;
                b0 += aB[4*q+0] * xB.x; b1 += aB[4*q+1] * xB.y;
                b2 += aB[4*q+2] * xB.z; b3 += aB[4*q+3] * xB.w;
            }
        }
        const float pjA = beA * ((a0 + a1) + (a2 + a3));
        const float pjB = beB * ((b0 + b1) + (b2 + b3));
        const float pmA = (j >= k) ? pjA : 0.f;
        const float pmB = (j >= k) ? pjB : 0.f;
        spA[j] = pmA;
        spB[j] = pmB;
        const float KA = grp32_sum(vjA * pmA);
        const float KB = grp32_sum(vjB * pmB);
        const float s2A = pmA - 2.f * (0.5f * beA * KA) * vjA;
        const float s2B = pmB - 2.f * (0.5f * beB * KB) * vjB;
        const float nvA = -vjA, nsA = -s2A;
        const float nvB = -vjB, nsB = -s2B;

        // rank-2 updates under HARD row guard; v/p re-read from LDS
        float ncA = colA, ncB = colB;
        if (j >= k) {
            #pragma unroll
            for (int q = 0; q < 8; ++q) {
                if (4*q + 3 >= k) {
                    const float4 xA = svA4[q]; const float4 pA = spA4[q];
                    const float4 xB = svB4[q]; const float4 pB = spB4[q];
                    #pragma unroll
                    for (int u = 0; u < 4; ++u) {
                        const int i = 4*q + u;
                        if (i >= k) {
                            const float xiA = (u==0)?xA.x:(u==1)?xA.y:(u==2)?xA.z:xA.w;
                            const float piA = (u==0)?pA.x:(u==1)?pA.y:(u==2)?pA.z:pA.w;
                            const float xiB = (u==0)?xB.x:(u==1)?xB.y:(u==2)?xB.z:xB.w;
                            const float piB = (u==0)?pB.x:(u==1)?pB.y:(u==2)?pB.z:pB.w;
                            float avA = aA[i];
                            avA = fmaf(nvA, piA, avA);
                            avA = fmaf(nsA, xiA, avA);
                            aA[i] = avA;
                            float avB = aB[i];
                            avB = fmaf(nvB, piB, avB);
                            avB = fmaf(nsB, xiB, avB);
                            aB[i] = avB;
                            ncA = (i == k + 1) ? avA : ncA;
                            ncB = (i == k + 1) ? avB : ncB;
                        }
                    }
                }
            }
        }
        colA = ncA; colB = ncB;
    }

    // ---- extraction: lane j keeps d_j, e_{j-1} (rows final by hard guard) ----
    float dA = 0.f, eA = 0.f, dB = 0.f, eB = 0.f;
    #pragma unroll
    for (int i = 0; i < NB; ++i) {
        dA = (i == j)     ? aA[i] : dA;
        eA = (i == j - 1) ? aA[i] : eA;
        dB = (i == j)     ? aB[i] : dB;
        eB = (i == j - 1) ? aB[i] : eB;
    }

    // Gershgorin bounds via DPP min/max reduces (independent chains)
    const float aeA = fabsf(eA), aeB = fabsf(eB);
    const float arA = __shfl(aeA, (j + 1) & 31, 32);
    const float arB = __shfl(aeB, (j + 1) & 31, 32);
    float loA = grp32_min(dA - (aeA + arA));
    float hiA = grp32_max(dA + (aeA + arA));
    float loB = grp32_min(dB - (aeB + arB));
    float hiB = grp32_max(dB + (aeB + arB));

    // publish d/e2 (same-wave producer/consumer, DS program order)
    *(float2*)&sde[g][0][j][0] = make_float2(dA, eA * eA);
    *(float2*)&sde[g][1][j][0] = make_float2(dB, eB * eB);

    // ---- phase 4: Sturm multisection, two interleaved chains ----
    const float2* deA2 = (const float2*)&sde[g][0][0][0];
    const float2* deB2 = (const float2*)&sde[g][1][0][0];
    for (int round = 0; round < 3; ++round) {
        asm volatile("" ::: "memory");   // no cross-round CSE of LDS loads
        const float stA = (hiA - loA) * (1.f / 33.f);
        const float stB = (hiB - loB) * (1.f / 33.f);
        const float siA = loA + stA * (float)(j + 1);
        const float siB = loB + stB * (float)(j + 1);
        float qA = deA2[0].x - siA;
        float qB = deB2[0].x - siB;
        int cA = (qA < 0.f), cB = (qB < 0.f);
        #pragma unroll
        for (int i = 1; i < NB; ++i) {
            const float2 dA2 = deA2[i];
            const float2 dB2 = deB2[i];
            if (fabsf(qA) < 1e-20f) qA = (qA < 0.f) ? -1e-20f : 1e-20f;
            if (fabsf(qB) < 1e-20f) qB = (qB < 0.f) ? -1e-20f : 1e-20f;
            qA = (dA2.x - siA) - dA2.y * __builtin_amdgcn_rcpf(qA);
            qB = (dB2.x - siB) - dB2.y * __builtin_amdgcn_rcpf(qB);
            cA += (qA < 0.f);
            cB += (qB < 0.f);
        }
        const unsigned long long balA = __ballot(cA >= 2);
        const unsigned long long balB = __ballot(cB >= 2);
        const unsigned int biA = (unsigned int)(balA >> (half * 32));
        const unsigned int biB = (unsigned int)(balB >> (half * 32));
        const int jsA = (biA == 0u) ? 32 : __builtin_ctz(biA);
        const int jsB = (biB == 0u) ? 32 : __builtin_ctz(biB);
        const float nlA = loA + stA * (float)jsA;
        const float nhA = loA + stA * (float)(jsA + 1);
        const float nlB = loB + stB * (float)jsB;
        const float nhB = loB + stB * (float)(jsB + 1);
        loA = nlA; hiA = nhA; loB = nlB; hiB = nhB;
    }
    const float lamA = 0.5f * (loA + hiA);
    const float lamB = 0.5f * (loB + hiB);

    if (j == 0) { out[2 + bA] = lamA; out[2 + bB] = lamB; }
    float ph = fmaxf(0.1f - lamA, 0.f) + fmaxf(0.1f - lamB, 0.f);
    const float ph0 = __shfl(ph, 0, 64);
    const float ph1 = __shfl(ph, 32, 64);
    if ((t & 63) == 0) atomicAdd(ws + 2, ph0 + ph1);   // 4 matrices per wave

}

__global__ __launch_bounds__(64)
void lap_final(float* __restrict__ out, const float* __restrict__ ws) {
    if (threadIdx.x == 0) {
        out[0] = ws[0] / fmaxf(ws[1], 1.f);
        out[1] = ws[2] * (1.f / (float)BATCH);
    }
}

extern "C" void kernel_launch(void* const* d_in, const int* in_sizes, int n_in,
                              void* d_out, int out_size, void* d_ws, size_t ws_size,
                              hipStream_t stream) {
    const float* pred = (const float*)d_in[0];
    const float* targ = (const float*)d_in[1];
    const float* nm   = (const float*)d_in[2];
    float* out = (float*)d_out;
    float* ws  = (float*)d_ws;

    (void)hipMemsetAsync(d_ws, 0, 16, stream);
    hipLaunchKernelGGL(lap_main, dim3(BATCH / MPB), dim3(TPB), 0, stream,
                       pred, targ, nm, out, ws);
    hipLaunchKernelGGL(lap_final, dim3(1), dim3(64), 0, stream, out, ws);
}

// Round 8
// 357.650 us; speedup vs baseline: 1.3293x; 1.2046x over previous
//
#include <hip/hip_runtime.h>
#include <math.h>

#define NB 32          // MAX_NODES
#define BATCH 16384
#define WPB 4          // waves (= matrices) per block
#define TPB (WPB * 64) // 256 threads

// ws layout (16 B, zeroed by hipMemsetAsync): [0]=bce_sum [1]=mask_sum [2]=phys_sum [3]=unused

// ---- DPP cross-lane helpers (VALU pipe) ----
template<int CTRL>
__device__ __forceinline__ float dpp_add(float v) {
    const int s = __float_as_int(v);
    const int r = __builtin_amdgcn_update_dpp(s, s, CTRL, 0xF, 0xF, false);
    return v + __int_as_float(r);
}
template<int CTRL>
__device__ __forceinline__ float dpp_min(float v) {
    const int s = __float_as_int(v);
    const int r = __builtin_amdgcn_update_dpp(s, s, CTRL, 0xF, 0xF, false);
    return fminf(v, __int_as_float(r));
}
template<int CTRL>
__device__ __forceinline__ float dpp_max(float v) {
    const int s = __float_as_int(v);
    const int r = __builtin_amdgcn_update_dpp(s, s, CTRL, 0xF, 0xF, false);
    return fmaxf(v, __int_as_float(r));
}
// sum with lane-pair partner (quad_perm [1,0,3,2] = 0xB1): result in both lanes
__device__ __forceinline__ float pair_sum(float v) { return dpp_add<0xB1>(v); }
// full 64-lane reduce-to-all
__device__ __forceinline__ float wave64_sum(float v) {
    v = dpp_add<0x121>(v); v = dpp_add<0x122>(v);
    v = dpp_add<0x124>(v); v = dpp_add<0x128>(v);
    v += __shfl_xor(v, 16, 64);
    v += __shfl_xor(v, 32, 64);
    return v;
}
__device__ __forceinline__ float wave64_min(float v) {
    v = dpp_min<0x121>(v); v = dpp_min<0x122>(v);
    v = dpp_min<0x124>(v); v = dpp_min<0x128>(v);
    v = fminf(v, __shfl_xor(v, 16, 64));
    return fminf(v, __shfl_xor(v, 32, 64));
}
__device__ __forceinline__ float wave64_max(float v) {
    v = dpp_max<0x121>(v); v = dpp_max<0x122>(v);
    v = dpp_max<0x124>(v); v = dpp_max<0x128>(v);
    v = fmaxf(v, __shfl_xor(v, 16, 64));
    return fmaxf(v, __shfl_xor(v, 32, 64));
}

// Round-8: ONE matrix per wave64, TWO lanes per row (each lane owns 16
// columns). Cross-round post-mortem: per-matrix cost has been invariant
// 13-17k cycles/CU across every structure because (a) 32+ live floats per
// thread forces AGPR/scratch juggling at the allocator's 64-VGPR fixation
// (R7: 136 MB scratch writes) and (b) the per-iter LDS/reduce chain is long.
// Half-rows give: a[16]+temps ~50 VGPR (true 64-reg fit, no juggling),
// per-iter FMA chains halved, pair ops on the VALU pipe via quad_perm DPP,
// 2x wave supply (16384 waves). HARD row guard j>=k kept (round-2 lesson);
// LDS v/p pre-masked with exact zeros; same-wave LDS producer/consumer
// (wave-synchronous, verified model from R6).
__global__ __launch_bounds__(TPB)
void lap_main(const float* __restrict__ predA, const float* __restrict__ targA,
              const float* __restrict__ nmask, float* __restrict__ out,
              float* __restrict__ ws)
{
    __shared__ float  sv[WPB][NB];     // masked Householder v (0 for r<=k)
    __shared__ float  sp[WPB][NB];     // masked p (0 for r<k)
    __shared__ float2 sde[WPB][NB];    // (d_r, e_{r-1}^2)
    __shared__ float  red[WPB][3];     // per-wave partials: bce, mask, phys

    const int t = threadIdx.x;            // 0..255
    const int w = t >> 6;                 // wave = matrix within block
    const int l = t & 63;                 // lane
    const int r = l >> 1;                 // row (0..31)
    const int h = l & 1;                  // column half (0..1)
    const int b = blockIdx.x * WPB + w;   // batch index
    const size_t base = (size_t)b * (NB * NB);

    // ---- phase 1: each lane loads its half-row (16 cols), BCE partials ----
    const float  mr  = nmask[(size_t)b * NB + r];
    const float4* pr4 = (const float4*)(predA + base + (size_t)r * NB + 16 * h);
    const float4* tr4 = (const float4*)(targA + base + (size_t)r * NB + 16 * h);
    const float4* nm4 = (const float4*)(nmask + (size_t)b * NB + 16 * h);

    float a[16];
    float accB = 0.f, accM = 0.f;
    #pragma unroll
    for (int q = 0; q < 4; ++q) {
        const float4 p  = pr4[q];
        const float4 tg = tr4[q];
        const float4 mc = nm4[q];
        const float bx = -(tg.x * __logf(p.x) + (1.f - tg.x) * __logf(1.f - p.x));
        const float by = -(tg.y * __logf(p.y) + (1.f - tg.y) * __logf(1.f - p.y));
        const float bz = -(tg.z * __logf(p.z) + (1.f - tg.z) * __logf(1.f - p.z));
        const float bw = -(tg.w * __logf(p.w) + (1.f - tg.w) * __logf(1.f - p.w));
        accB += mr * (mc.x * bx + mc.y * by + mc.z * bz + mc.w * bw);
        accM += mr * (mc.x + mc.y + mc.z + mc.w);
        a[4*q+0] = p.x; a[4*q+1] = p.y; a[4*q+2] = p.z; a[4*q+3] = p.w;
    }
    // (accB/accM stay in 2 regs; reduced + accumulated at kernel end)

    // ---- phase 2: M = (L+L^T)/2 in place ----
    float dsl = 0.f, pdl = 0.f;
    #pragma unroll
    for (int u = 0; u < 16; ++u) {
        dsl += a[u];
        pdl = (16 * h + u == r) ? a[u] : pdl;   // at most one lane-slot matches
    }
    const float dsum  = pair_sum(dsl);          // full row sum, both pair lanes
    const float pdiag = pair_sum((16 * h + ((r & 15)) == r) ? 0.f : 0.f) * 0.f + pair_sum(pdl);
    const float jitter = 1e-5f + (9e-5f / 31.f) * (float)r;
    const float dval = dsum + jitter - pdiag;
    #pragma unroll
    for (int q = 0; q < 4; ++q) {
        #pragma unroll
        for (int u = 0; u < 4; ++u) {
            const int cl = 4 * q + u;
            const int c  = 16 * h + cl;                      // global column
            const float cv = predA[base + (size_t)c * NB + r]; // P[c][r]
            a[cl] = (c == r) ? dval : -0.5f * (a[cl] + cv);
        }
    }

    // colk init: column 0 = A[r][0], owned by h==0 slot 0
    {
        const float cap0 = (h == 0) ? a[0] : 0.f;
        // pair partner add: owner contributes value, other contributes 0
        float ck = pair_sum(cap0);
        // (works because non-owner contributed 0)
        a[0] = a[0]; // no-op
        // stash into colk below
        // (scoped to keep register naming clear)
        // fallthrough
        // colk declared next
        // --
        // NOTE: kept trivially simple on purpose
        (void)ck;
    }
    float colk;
    {
        const float cap0 = (h == 0) ? a[0] : 0.f;
        colk = pair_sum(cap0);
    }

    // ---- phase 3: Householder tridiagonalization, half-row layout ----
    const float4* v4h = (const float4*)&sv[w][16 * h];  // my half of v
    const float4* p4h = (const float4*)&sp[w][16 * h];  // my half of p
    for (int k = 0; k < NB - 2; ++k) {
        // sg = sum_{r>k} colk^2 (pairs duplicate colk -> count h==0 only)
        const float sg = wave64_sum((h == 0 && r > k) ? colk * colk : 0.f);
        const float x1 = __shfl(colk, 2 * (k + 1), 64);   // row k+1's colk
        const float al = (x1 >= 0.f) ? -sqrtf(sg) : sqrtf(sg);
        const float denom = sg - al * x1;
        const float beta  = (denom > 1e-30f) ? __builtin_amdgcn_rcpf(denom) : 0.f;
        const float vj = (r > k) ? (colk - ((r == k + 1) ? al : 0.f)) : 0.f;
        if (h == 0) sv[w][r] = vj;          // pre-masked: exact 0 for r<=k

        // dot = row . v over my 16 cols (LDS b128 broadcast of my half)
        float ac0 = 0.f, ac1 = 0.f, ac2 = 0.f, ac3 = 0.f;
        #pragma unroll
        for (int q = 0; q < 4; ++q) {
            if (16 + 4 * q + 3 >= k) {      // uniform skip: both halves dead
                const float4 x = v4h[q];
                ac0 += a[4*q+0] * x.x;
                ac1 += a[4*q+1] * x.y;
                ac2 += a[4*q+2] * x.z;
                ac3 += a[4*q+3] * x.w;
            }
        }
        const float dhalf = (ac0 + ac1) + (ac2 + ac3);
        const float dot = pair_sum(dhalf);  // full row dot, both lanes
        const float pj  = beta * dot;
        const float pjm = (r >= k) ? pj : 0.f;
        if (h == 0) sp[w][r] = pjm;
        const float K  = wave64_sum((h == 0) ? vj * pjm : 0.f);
        const float c2 = 0.5f * beta * K;
        const float s2 = pjm - 2.f * c2 * vj;
        const float nv = -vj, ns = -s2;

        // rank-2 update under HARD row guard; v/p halves re-read from LDS
        float cap = 0.f;
        if (r >= k) {
            #pragma unroll
            for (int q = 0; q < 4; ++q) {
                if (16 + 4 * q + 3 >= k) {
                    const float4 x4 = v4h[q];
                    const float4 p4 = p4h[q];
                    #pragma unroll
                    for (int u = 0; u < 4; ++u) {
                        const int cl = 4 * q + u;
                        const float xv = (u==0)?x4.x:(u==1)?x4.y:(u==2)?x4.z:x4.w;
                        const float pv = (u==0)?p4.x:(u==1)?p4.y:(u==2)?p4.z:p4.w;
                        float av = a[cl];
                        av = fmaf(nv, pv, av);
                        av = fmaf(ns, xv, av);
                        a[cl] = av;
                        cap = (16 * h + cl == k + 1) ? av : cap; // col k+1
                    }
                }
            }
        }
        colk = pair_sum(cap);   // owner half supplies value, other 0;
                                // frozen rows get 0 (unused: all consumers mask r>k)
    }

    // ---- extraction: d_r = A[r][r], e_{r-1} = A[r][r-1] ----
    float dl = 0.f, el = 0.f;
    #pragma unroll
    for (int u = 0; u < 16; ++u) {
        dl = (16 * h + u == r)     ? a[u] : dl;
        el = (16 * h + u == r - 1) ? a[u] : el;   // r=0: stays 0
    }
    const float d = pair_sum(dl);
    const float e = pair_sum(el);
    if (h == 0) sde[w][r] = make_float2(d, e * e);

    // Gershgorin bounds (pairs duplicate -> harmless for min/max)
    const float ae  = fabsf(e);                            // |e_{r-1}|
    const float aen = (r == 31) ? 0.f : __shfl(ae, (l + 2) & 63, 64); // |e_r|
    float lo = wave64_min(d - (ae + aen));
    float hi = wave64_max(d + (ae + aen));

    // ---- phase 4: Sturm multisection, 64 sigmas/round, 3 rounds ----
    const float2* de = (const float2*)&sde[w][0];
    for (int round = 0; round < 3; ++round) {
        asm volatile("" ::: "memory");   // no cross-round CSE of LDS loads
        const float step = (hi - lo) * (1.f / 65.f);
        const float sig = lo + step * (float)(l + 1);
        float q = de[0].x - sig;
        int cnt = (q < 0.f);
        #pragma unroll
        for (int i = 1; i < NB; ++i) {
            const float2 di = de[i];
            if (fabsf(q) < 1e-20f) q = (q < 0.f) ? -1e-20f : 1e-20f;
            q = (di.x - sig) - di.y * __builtin_amdgcn_rcpf(q);
            cnt += (q < 0.f);
        }
        const unsigned long long bal = __ballot(cnt >= 2);
        const int jstar = (bal == 0ull) ? 64 : __builtin_ctzll(bal);
        const float nlo = lo + step * (float)jstar;
        const float nhi = lo + step * (float)(jstar + 1);
        lo = nlo; hi = nhi;
    }
    const float lam2 = 0.5f * (lo + hi);

    if (l == 0) out[2 + b] = lam2;

    // ---- final: per-wave reduce of bce/mask partials + phys; 3 atomics/block
    const float accBs = wave64_sum(accB);
    const float accMs = wave64_sum(accM);
    const float ph = fmaxf(0.1f - lam2, 0.f);
    if (l == 0) { red[w][0] = accBs; red[w][1] = accMs; red[w][2] = ph; }
    __syncthreads();
    if (t == 0) {
        float sB = 0.f, sM = 0.f, sP = 0.f;
        #pragma unroll
        for (int i = 0; i < WPB; ++i) { sB += red[i][0]; sM += red[i][1]; sP += red[i][2]; }
        atomicAdd(ws + 0, sB);
        atomicAdd(ws + 1, sM);
        atomicAdd(ws + 2, sP);
    }
}

__global__ __launch_bounds__(64)
void lap_final(float* __restrict__ out, const float* __restrict__ ws) {
    if (threadIdx.x == 0) {
        out[0] = ws[0] / fmaxf(ws[1], 1.f);
        out[1] = ws[2] * (1.f / (float)BATCH);
    }
}

extern "C" void kernel_launch(void* const* d_in, const int* in_sizes, int n_in,
                              void* d_out, int out_size, void* d_ws, size_t ws_size,
                              hipStream_t stream) {
    const float* pred = (const float*)d_in[0];
    const float* targ = (const float*)d_in[1];
    const float* nm   = (const float*)d_in[2];
    float* out = (float*)d_out;
    float* ws  = (float*)d_ws;

    (void)hipMemsetAsync(d_ws, 0, 16, stream);
    hipLaunchKernelGGL(lap_main, dim3(BATCH / WPB), dim3(TPB), 0, stream,
                       pred, targ, nm, out, ws);
    hipLaunchKernelGGL(lap_final, dim3(1), dim3(64), 0, stream, out, ws);
}

// Round 9
// 336.893 us; speedup vs baseline: 1.4112x; 1.0616x over previous
//
#include <hip/hip_runtime.h>
#include <math.h>

#define NB 32          // MAX_NODES
#define BATCH 16384
#define WPB 4          // waves per block; each wave owns TWO matrices
#define TPB (WPB * 64) // 256 threads
#define MPB (WPB * 2)  // 8 matrices per block

// ws layout (16 B, zeroed by hipMemsetAsync): [0]=bce_sum [1]=mask_sum [2]=phys_sum [3]=unused

// ---- DPP cross-lane helpers (VALU pipe) ----
template<int CTRL>
__device__ __forceinline__ float dpp_add(float v) {
    const int s = __float_as_int(v);
    const int r = __builtin_amdgcn_update_dpp(s, s, CTRL, 0xF, 0xF, false);
    return v + __int_as_float(r);
}
template<int CTRL>
__device__ __forceinline__ float dpp_min(float v) {
    const int s = __float_as_int(v);
    const int r = __builtin_amdgcn_update_dpp(s, s, CTRL, 0xF, 0xF, false);
    return fminf(v, __int_as_float(r));
}
template<int CTRL>
__device__ __forceinline__ float dpp_max(float v) {
    const int s = __float_as_int(v);
    const int r = __builtin_amdgcn_update_dpp(s, s, CTRL, 0xF, 0xF, false);
    return fmaxf(v, __int_as_float(r));
}
// sum with lane-pair partner (quad_perm [1,0,3,2] = 0xB1): result in both lanes
__device__ __forceinline__ float pair_sum(float v) { return dpp_add<0xB1>(v); }
// full 64-lane reduce-to-all
__device__ __forceinline__ float wave64_sum(float v) {
    v = dpp_add<0x121>(v); v = dpp_add<0x122>(v);
    v = dpp_add<0x124>(v); v = dpp_add<0x128>(v);
    v += __shfl_xor(v, 16, 64);
    v += __shfl_xor(v, 32, 64);
    return v;
}
__device__ __forceinline__ float wave64_min(float v) {
    v = dpp_min<0x121>(v); v = dpp_min<0x122>(v);
    v = dpp_min<0x124>(v); v = dpp_min<0x128>(v);
    v = fminf(v, __shfl_xor(v, 16, 64));
    return fminf(v, __shfl_xor(v, 32, 64));
}
__device__ __forceinline__ float wave64_max(float v) {
    v = dpp_max<0x121>(v); v = dpp_max<0x122>(v);
    v = dpp_max<0x124>(v); v = dpp_max<0x128>(v);
    v = fmaxf(v, __shfl_xor(v, 16, 64));
    return fmaxf(v, __shfl_xor(v, 32, 64));
}

// Round-9: R8's half-row layout (2 lanes/row, a[16], verified 259us) with an
// ILP PAIR of matrices per wave. R8 post-mortem: per-iter serial chain
// (~320cy: 2 LDS round-trips + reduce + sqrt/rcp) x 30 iters == measured
// 9.7k cy/matrix; VALU only 63% fed. Two independent chains per wave cover
// 2 matrices per chain window. R7's pair failed at 64+64 floats (no tier
// fit -> 136MB scratch); half-row pair is ~100 regs -> fits the 128 tier.
// __launch_bounds__(TPB,4): VGPR cap exactly 128.
// Verified invariants kept verbatim per chain: HARD row guard (round-2
// lesson), pre-masked LDS v/p (exact zeros), same-wave LDS producer/consumer,
// DPP reduces, 3-round 64-section Sturm.
__global__ __launch_bounds__(TPB, 4)
void lap_main(const float* __restrict__ predA, const float* __restrict__ targA,
              const float* __restrict__ nmask, float* __restrict__ out,
              float* __restrict__ ws)
{
    __shared__ float  svA_[WPB][NB], svB_[WPB][NB];   // masked v (0 for r<=k)
    __shared__ float  spA_[WPB][NB], spB_[WPB][NB];   // masked p (0 for r<k)
    __shared__ float2 sdeA_[WPB][NB], sdeB_[WPB][NB]; // (d_r, e_{r-1}^2)
    __shared__ float  red[WPB][3];                    // bce, mask, phys

    const int t = threadIdx.x;            // 0..255
    const int w = t >> 6;                 // wave within block
    const int l = t & 63;                 // lane
    const int r = l >> 1;                 // row (0..31)
    const int h = l & 1;                  // column half (0..1)
    const int bA = blockIdx.x * MPB + w * 2;
    const int bB = bA + 1;
    const size_t baseA = (size_t)bA * (NB * NB);
    const size_t baseB = (size_t)bB * (NB * NB);

    // ---- phase 1: half-row loads + BCE partials, A then B ----
    const float mrA = nmask[(size_t)bA * NB + r];
    const float mrB = nmask[(size_t)bB * NB + r];
    const float4* prA = (const float4*)(predA + baseA + (size_t)r * NB + 16 * h);
    const float4* trA = (const float4*)(targA + baseA + (size_t)r * NB + 16 * h);
    const float4* nmA = (const float4*)(nmask + (size_t)bA * NB + 16 * h);
    const float4* prB = (const float4*)(predA + baseB + (size_t)r * NB + 16 * h);
    const float4* trB = (const float4*)(targA + baseB + (size_t)r * NB + 16 * h);
    const float4* nmB = (const float4*)(nmask + (size_t)bB * NB + 16 * h);

    float aA[16], aB[16];
    float accB = 0.f, accM = 0.f;
    #pragma unroll
    for (int q = 0; q < 4; ++q) {
        const float4 p  = prA[q];
        const float4 tg = trA[q];
        const float4 mc = nmA[q];
        const float bx = -(tg.x * __logf(p.x) + (1.f - tg.x) * __logf(1.f - p.x));
        const float by = -(tg.y * __logf(p.y) + (1.f - tg.y) * __logf(1.f - p.y));
        const float bz = -(tg.z * __logf(p.z) + (1.f - tg.z) * __logf(1.f - p.z));
        const float bw = -(tg.w * __logf(p.w) + (1.f - tg.w) * __logf(1.f - p.w));
        accB += mrA * (mc.x * bx + mc.y * by + mc.z * bz + mc.w * bw);
        accM += mrA * (mc.x + mc.y + mc.z + mc.w);
        aA[4*q+0] = p.x; aA[4*q+1] = p.y; aA[4*q+2] = p.z; aA[4*q+3] = p.w;
    }
    #pragma unroll
    for (int q = 0; q < 4; ++q) {
        const float4 p  = prB[q];
        const float4 tg = trB[q];
        const float4 mc = nmB[q];
        const float bx = -(tg.x * __logf(p.x) + (1.f - tg.x) * __logf(1.f - p.x));
        const float by = -(tg.y * __logf(p.y) + (1.f - tg.y) * __logf(1.f - p.y));
        const float bz = -(tg.z * __logf(p.z) + (1.f - tg.z) * __logf(1.f - p.z));
        const float bw = -(tg.w * __logf(p.w) + (1.f - tg.w) * __logf(1.f - p.w));
        accB += mrB * (mc.x * bx + mc.y * by + mc.z * bz + mc.w * bw);
        accM += mrB * (mc.x + mc.y + mc.z + mc.w);
        aB[4*q+0] = p.x; aB[4*q+1] = p.y; aB[4*q+2] = p.z; aB[4*q+3] = p.w;
    }

    // ---- phase 2: M = (L+L^T)/2 in place (both matrices) ----
    float dslA = 0.f, pdlA = 0.f, dslB = 0.f, pdlB = 0.f;
    #pragma unroll
    for (int u = 0; u < 16; ++u) {
        dslA += aA[u]; pdlA = (16 * h + u == r) ? aA[u] : pdlA;
        dslB += aB[u]; pdlB = (16 * h + u == r) ? aB[u] : pdlB;
    }
    const float jitter = 1e-5f + (9e-5f / 31.f) * (float)r;
    const float dvA = pair_sum(dslA) + jitter - pair_sum(pdlA);
    const float dvB = pair_sum(dslB) + jitter - pair_sum(pdlB);
    #pragma unroll
    for (int u = 0; u < 16; ++u) {
        const int c = 16 * h + u;                            // global column
        const float cvA = predA[baseA + (size_t)c * NB + r]; // P[c][r] (L1-hit)
        const float cvB = predA[baseB + (size_t)c * NB + r];
        aA[u] = (c == r) ? dvA : -0.5f * (aA[u] + cvA);
        aB[u] = (c == r) ? dvB : -0.5f * (aB[u] + cvB);
    }

    // colk init: column 0 = A[r][0], owned by h==0 slot 0
    float colA, colB;
    {
        const float c0A = (h == 0) ? aA[0] : 0.f;
        const float c0B = (h == 0) ? aB[0] : 0.f;
        colA = pair_sum(c0A);
        colB = pair_sum(c0B);
    }

    // ---- phase 3: Householder, two interleaved independent chains ----
    float* svA = &svA_[w][0]; float* svB = &svB_[w][0];
    float* spA = &spA_[w][0]; float* spB = &spB_[w][0];
    const float4* vA4 = (const float4*)&svA[16 * h];
    const float4* vB4 = (const float4*)&svB[16 * h];
    const float4* pA4 = (const float4*)&spA[16 * h];
    const float4* pB4 = (const float4*)&spB[16 * h];
    for (int k = 0; k < NB - 2; ++k) {
        const float sgA = wave64_sum((h == 0 && r > k) ? colA * colA : 0.f);
        const float sgB = wave64_sum((h == 0 && r > k) ? colB * colB : 0.f);
        const float x1A = __shfl(colA, 2 * (k + 1), 64);
        const float x1B = __shfl(colB, 2 * (k + 1), 64);
        const float alA = (x1A >= 0.f) ? -sqrtf(sgA) : sqrtf(sgA);
        const float alB = (x1B >= 0.f) ? -sqrtf(sgB) : sqrtf(sgB);
        const float deA = sgA - alA * x1A;
        const float deB = sgB - alB * x1B;
        const float beA = (deA > 1e-30f) ? __builtin_amdgcn_rcpf(deA) : 0.f;
        const float beB = (deB > 1e-30f) ? __builtin_amdgcn_rcpf(deB) : 0.f;
        const float vjA = (r > k) ? (colA - ((r == k + 1) ? alA : 0.f)) : 0.f;
        const float vjB = (r > k) ? (colB - ((r == k + 1) ? alB : 0.f)) : 0.f;
        if (h == 0) { svA[r] = vjA; svB[r] = vjB; }  // pre-masked: 0 for r<=k

        // dots over my 16 cols via uniform-address b128 broadcasts
        float a0 = 0.f, a1 = 0.f, a2 = 0.f, a3 = 0.f;
        float b0 = 0.f, b1 = 0.f, b2 = 0.f, b3 = 0.f;
        #pragma unroll
        for (int q = 0; q < 4; ++q) {
            if (16 + 4 * q + 3 >= k) {      // wave-uniform conservative skip
                const float4 xA = vA4[q];
                const float4 xB = vB4[q];
                a0 += aA[4*q+0] * xA.x; a1 += aA[4*q+1] * xA.y;
                a2 += aA[4*q+2] * xA.z; a3 += aA[4*q+3] * xA.w;
                b0 += aB[4*q+0] * xB.x; b1 += aB[4*q+1] * xB.y;
                b2 += aB[4*q+2] * xB.z; b3 += aB[4*q+3] * xB.w;
            }
        }
        const float dotA = pair_sum((a0 + a1) + (a2 + a3));
        const float dotB = pair_sum((b0 + b1) + (b2 + b3));
        const float pjA = beA * dotA;
        const float pjB = beB * dotB;
        const float pmA = (r >= k) ? pjA : 0.f;
        const float pmB = (r >= k) ? pjB : 0.f;
        if (h == 0) { spA[r] = pmA; spB[r] = pmB; }
        const float KA = wave64_sum((h == 0) ? vjA * pmA : 0.f);
        const float KB = wave64_sum((h == 0) ? vjB * pmB : 0.f);
        const float s2A = pmA - 2.f * (0.5f * beA * KA) * vjA;
        const float s2B = pmB - 2.f * (0.5f * beB * KB) * vjB;
        const float nvA = -vjA, nsA = -s2A;
        const float nvB = -vjB, nsB = -s2B;

        // rank-2 updates under HARD row guard; v/p re-read from LDS
        float capA = 0.f, capB = 0.f;
        if (r >= k) {
            #pragma unroll
            for (int q = 0; q < 4; ++q) {
                if (16 + 4 * q + 3 >= k) {
                    const float4 xA = vA4[q]; const float4 pA = pA4[q];
                    const float4 xB = vB4[q]; const float4 pB = pB4[q];
                    #pragma unroll
                    for (int u = 0; u < 4; ++u) {
                        const int cl = 4 * q + u;
                        const float xvA = (u==0)?xA.x:(u==1)?xA.y:(u==2)?xA.z:xA.w;
                        const float pvA = (u==0)?pA.x:(u==1)?pA.y:(u==2)?pA.z:pA.w;
                        const float xvB = (u==0)?xB.x:(u==1)?xB.y:(u==2)?xB.z:xB.w;
                        const float pvB = (u==0)?pB.x:(u==1)?pB.y:(u==2)?pB.z:pB.w;
                        float vA = aA[cl];
                        vA = fmaf(nvA, pvA, vA);
                        vA = fmaf(nsA, xvA, vA);
                        aA[cl] = vA;
                        float vB = aB[cl];
                        vB = fmaf(nvB, pvB, vB);
                        vB = fmaf(nsB, xvB, vB);
                        aB[cl] = vB;
                        capA = (16 * h + cl == k + 1) ? vA : capA;
                        capB = (16 * h + cl == k + 1) ? vB : capB;
                    }
                }
            }
        }
        colA = pair_sum(capA);   // frozen rows get 0 (consumers mask r>k)
        colB = pair_sum(capB);
    }

    // ---- extraction: d_r = A[r][r], e_{r-1} = A[r][r-1] ----
    float dlA = 0.f, elA = 0.f, dlB = 0.f, elB = 0.f;
    #pragma unroll
    for (int u = 0; u < 16; ++u) {
        dlA = (16 * h + u == r)     ? aA[u] : dlA;
        elA = (16 * h + u == r - 1) ? aA[u] : elA;
        dlB = (16 * h + u == r)     ? aB[u] : dlB;
        elB = (16 * h + u == r - 1) ? aB[u] : elB;
    }
    const float dA = pair_sum(dlA);
    const float eA = pair_sum(elA);
    const float dB = pair_sum(dlB);
    const float eB = pair_sum(elB);
    if (h == 0) { sdeA_[w][r] = make_float2(dA, eA * eA);
                  sdeB_[w][r] = make_float2(dB, eB * eB); }

    // Gershgorin bounds (pair-duplicated values are harmless for min/max)
    const float aeA = fabsf(eA), aeB = fabsf(eB);
    const float anA = (r == 31) ? 0.f : __shfl(aeA, (l + 2) & 63, 64);
    const float anB = (r == 31) ? 0.f : __shfl(aeB, (l + 2) & 63, 64);
    float loA = wave64_min(dA - (aeA + anA));
    float hiA = wave64_max(dA + (aeA + anA));
    float loB = wave64_min(dB - (aeB + anB));
    float hiB = wave64_max(dB + (aeB + anB));

    // ---- phase 4: Sturm multisection, interleaved chains, 64 sigmas ----
    const float2* deA = (const float2*)&sdeA_[w][0];
    const float2* deB = (const float2*)&sdeB_[w][0];
    for (int round = 0; round < 3; ++round) {
        asm volatile("" ::: "memory");   // no cross-round CSE of LDS loads
        const float stA = (hiA - loA) * (1.f / 65.f);
        const float stB = (hiB - loB) * (1.f / 65.f);
        const float siA = loA + stA * (float)(l + 1);
        const float siB = loB + stB * (float)(l + 1);
        float qA = deA[0].x - siA;
        float qB = deB[0].x - siB;
        int cA = (qA < 0.f), cB = (qB < 0.f);
        #pragma unroll
        for (int i = 1; i < NB; ++i) {
            const float2 diA = deA[i];
            const float2 diB = deB[i];
            if (fabsf(qA) < 1e-20f) qA = (qA < 0.f) ? -1e-20f : 1e-20f;
            if (fabsf(qB) < 1e-20f) qB = (qB < 0.f) ? -1e-20f : 1e-20f;
            qA = (diA.x - siA) - diA.y * __builtin_amdgcn_rcpf(qA);
            qB = (diB.x - siB) - diB.y * __builtin_amdgcn_rcpf(qB);
            cA += (qA < 0.f);
            cB += (qB < 0.f);
        }
        const unsigned long long balA = __ballot(cA >= 2);
        const unsigned long long balB = __ballot(cB >= 2);
        const int jsA = (balA == 0ull) ? 64 : __builtin_ctzll(balA);
        const int jsB = (balB == 0ull) ? 64 : __builtin_ctzll(balB);
        const float nlA = loA + stA * (float)jsA;
        const float nhA = loA + stA * (float)(jsA + 1);
        const float nlB = loB + stB * (float)jsB;
        const float nhB = loB + stB * (float)(jsB + 1);
        loA = nlA; hiA = nhA; loB = nlB; hiB = nhB;
    }
    const float lamA = 0.5f * (loA + hiA);
    const float lamB = 0.5f * (loB + hiB);

    if (l == 0) { out[2 + bA] = lamA; out[2 + bB] = lamB; }

    // ---- final: per-wave reduce + 3 atomics per block ----
    const float accBs = wave64_sum(accB);
    const float accMs = wave64_sum(accM);
    const float ph = fmaxf(0.1f - lamA, 0.f) + fmaxf(0.1f - lamB, 0.f);
    if (l == 0) { red[w][0] = accBs; red[w][1] = accMs; red[w][2] = ph; }
    __syncthreads();
    if (t == 0) {
        float sB = 0.f, sM = 0.f, sP = 0.f;
        #pragma unroll
        for (int i = 0; i < WPB; ++i) { sB += red[i][0]; sM += red[i][1]; sP += red[i][2]; }
        atomicAdd(ws + 0, sB);
        atomicAdd(ws + 1, sM);
        atomicAdd(ws + 2, sP);
    }
}

__global__ __launch_bounds__(64)
void lap_final(float* __restrict__ out, const float* __restrict__ ws) {
    if (threadIdx.x == 0) {
        out[0] = ws[0] / fmaxf(ws[1], 1.f);
        out[1] = ws[2] * (1.f / (float)BATCH);
    }
}

extern "C" void kernel_launch(void* const* d_in, const int* in_sizes, int n_in,
                              void* d_out, int out_size, void* d_ws, size_t ws_size,
                              hipStream_t stream) {
    const float* pred = (const float*)d_in[0];
    const float* targ = (const float*)d_in[1];
    const float* nm   = (const float*)d_in[2];
    float* out = (float*)d_out;
    float* ws  = (float*)d_ws;

    (void)hipMemsetAsync(d_ws, 0, 16, stream);
    hipLaunchKernelGGL(lap_main, dim3(BATCH / MPB), dim3(TPB), 0, stream,
                       pred, targ, nm, out, ws);
    hipLaunchKernelGGL(lap_final, dim3(1), dim3(64), 0, stream, out, ws);
}